// Round 5
// baseline (275.813 us; speedup 1.0000x reference)
//
#include <hip/hip_runtime.h>
#include <stdint.h>

// CycleFC 1w1a: out[b,o,h,w] = sum_c sign(x)[b,c,h,w+off(c)] * sign(W)[o,c] + bias[o]
// off(c) = (c+3)%7 - 3, zero-pad OOB. B=64, C=O=384, H=W=32.
//
// Binary-GEMM: pack signs (bit=1 iff <0) into 6 u64 words; out = bias2 - 2*popc(G^WB).
// bias2w[o][w] = bias[o] + Nvalid(w) + 2*popc(WB & ~V(w)) precomputed in prep.
//
// R10: R9 disproved spill (VGPR fit, time unchanged). Invariant across R5-R9:
// VALU busy ~20us, wall ~70us, all waves stalled together -> the two things
// every variant shared: (1) per-iteration wave-uniform s_load weight fetches
// (SMEM is unordered -> full lgkmcnt drain each tile, all waves in lockstep),
// (2) fully-unrolled ~30KB bodies (I$ streaming, paid by all waves).
// Fix both: weights for the wave's 4 o-channels preloaded to SGPRs ONCE
// (zero scalar loads in the loop); full-image G in LDS (32x32x7 u64 = 57KB,
// pad 6->7 cuts read conflict 8way->4way); compact '#pragma unroll 2' loops.
// Block = (b, o/8): 768thr=12 waves, grid 512 = 2 blocks/CU, one barrier.
// Pack math (pre-transpose shift + shfl_xor butterfly) verified R7-R9.

#define IN_CH 384
#define HH 32
#define WW 32
#define BB 64

constexpr uint64_t P7(int t) {
  uint64_t m = 0;
  for (int k = 0; k < 64; ++k)
    if (k % 7 == t) m |= (1ull << k);
  return m;
}
__device__ __constant__ uint64_t Pm[7] = {P7(0), P7(1), P7(2), P7(3), P7(4), P7(5), P7(6)};

// ---------------- prep: one block (1 wave) per output channel o --------------
__global__ __launch_bounds__(64) void cyc_prep(const float* __restrict__ wgt,
                                               const float* __restrict__ bias,
                                               uint64_t* __restrict__ wbg,
                                               float* __restrict__ bias2w) {
  const int o = blockIdx.x;
  const int lane = threadIdx.x;
  __shared__ uint64_t wb_sh[6];
#pragma unroll
  for (int j = 0; j < 6; ++j) {
    uint64_t m = __ballot(wgt[o * IN_CH + j * 64 + lane] < 0.0f);
    if (lane == 0) wb_sh[j] = m;
  }
  __syncthreads();
  if (lane < 6) wbg[o * 6 + lane] = wb_sh[lane];
  if (lane < WW) {
    const int w = lane;
    int nv = 0, corr = 0;
#pragma unroll
    for (int j = 0; j < 6; ++j) {
      uint64_t V = 0;
#pragma unroll
      for (int d = -3; d <= 3; ++d) {
        int wd = w + d;
        if (wd >= 0 && wd < WW) V |= Pm[(d - j + 14) % 7];
      }
      nv += __popcll(V);
      corr += __popcll(wb_sh[j] & ~V);
    }
    // layout [o][w]: gemm bias loads are 128B coalesced per o
    bias2w[o * WW + w] = bias[o] + (float)nv + 2.0f * (float)corr;
  }
}

// ------- fused main: block = (b, o-eighth), 768 thr = 12 waves ---------------
__global__ __launch_bounds__(768) void cyc_fused(const float* __restrict__ x,
                                                 const uint64_t* __restrict__ wbg,
                                                 const float* __restrict__ bias2w,
                                                 float* __restrict__ out) {
  // [row][w][j] with j padded 6->7: read stride 56B -> 4-way bank conflict max
  __shared__ uint64_t sh_G[HH * WW * 7];  // 57344 B
  const int t = threadIdx.x;
  const int lane = t & 63, wave = t >> 6;
  const int bid = blockIdx.x;  // grid = 64*8 = 512
  const int oq = bid & 7;
  const int b = bid >> 3;

  // ---- pack: all 32 rows x 6 ch-groups = 192 tasks, 16 per wave.
  {
    uint32_t* shw = (uint32_t*)sh_G;
    const int wcol = lane & 31, hhalf = lane >> 5;
#pragma unroll 2
    for (int p = 0; p < 16; ++p) {
      const int tau = wave * 16 + p;
      const int r = tau / 6, j = tau % 6;
      const int c = j * 64 + lane;
      const int off = ((c % 7 + 3) % 7) - 3;  // in [-3,3]
      const uint32_t shr = (off > 0) ? (uint32_t)off : 0u;
      const uint32_t shl = (off < 0) ? (uint32_t)(-off) : 0u;
      const float4* xp = reinterpret_cast<const float4*>(
          x + (size_t)((b * IN_CH + c) * HH + r) * WW);
      uint32_t myw = 0;
#pragma unroll
      for (int i = 0; i < 8; ++i) {
        float4 v = xp[i];
        myw |= (v.x < 0.0f ? 1u : 0u) << (i * 4 + 0);
        myw |= (v.y < 0.0f ? 1u : 0u) << (i * 4 + 1);
        myw |= (v.z < 0.0f ? 1u : 0u) << (i * 4 + 2);
        myw |= (v.w < 0.0f ? 1u : 0u) << (i * 4 + 3);
      }
      // pre-transpose cycle shift: bit w := myw bit (w+off); zero-fill == OOB pad
      uint32_t s = (myw >> shr) << shl;  // one of shr/shl is 0
      // 5-step 32x32 bit transpose across each 32-lane half (verified R7-R9).
      constexpr uint32_t Mt[5] = {0xFFFF0000u, 0xFF00FF00u, 0xF0F0F0F0u,
                                  0xCCCCCCCCu, 0xAAAAAAAAu};
#pragma unroll
      for (int stp = 0; stp < 5; ++stp) {
        const int js = 16 >> stp;
        const uint32_t M = Mt[stp];
        uint32_t y = __shfl_xor(s, js);
        s = (lane & js) ? ((s & M) | ((y >> js) & ~M))
                        : ((s & ~M) | ((y << js) & M));
      }
      // u32 half hhalf of u64 sh_G[(r*32 + wcol)*7 + j]
      shw[((r * WW + wcol) * 7 + j) * 2 + hhalf] = s;
    }
  }
  __syncthreads();

  // ---- gemm: wave owns 4 o-channels; weights -> SGPRs ONCE, bias -> 4 VGPRs.
  // Inner loop: ds_read only (in-order, counted) + VALU + stores. No s_load.
  const int wu = __builtin_amdgcn_readfirstlane(wave);
  const int o0 = oq * 48 + wu * 4;
  const uint64_t* wp = wbg + (size_t)o0 * 6;
  uint64_t Wg[4][6];
#pragma unroll
  for (int oo = 0; oo < 4; ++oo)
#pragma unroll
    for (int j = 0; j < 6; ++j) Wg[oo][j] = wp[oo * 6 + j];

  const int w = lane & 31;
  float bs[4];
#pragma unroll
  for (int oo = 0; oo < 4; ++oo) bs[oo] = bias2w[(o0 + oo) * WW + w];

  // pixel index = 64*p + lane == row (2p + lane/32), col (lane%32);
  // store offset below uses the same 64*p + lane -> 256B contiguous per store.
  float* op = out + ((size_t)b * IN_CH + o0) * (HH * WW) + lane;
#pragma unroll 2
  for (int p = 0; p < 16; ++p) {
    const uint64_t* gp = sh_G + (size_t)(64 * p + lane) * 7;
    const uint64_t g0 = gp[0], g1 = gp[1], g2 = gp[2];
    const uint64_t g3 = gp[3], g4 = gp[4], g5 = gp[5];
#pragma unroll
    for (int oo = 0; oo < 4; ++oo) {
      int mm = __popcll(g0 ^ Wg[oo][0]) + __popcll(g1 ^ Wg[oo][1]) +
               __popcll(g2 ^ Wg[oo][2]) + __popcll(g3 ^ Wg[oo][3]) +
               __popcll(g4 ^ Wg[oo][4]) + __popcll(g5 ^ Wg[oo][5]);
      op[oo * (HH * WW) + p * 64] = bs[oo] - 2.0f * (float)mm;
    }
  }
}

extern "C" void kernel_launch(void* const* d_in, const int* in_sizes, int n_in,
                              void* d_out, int out_size, void* d_ws, size_t ws_size,
                              hipStream_t stream) {
  const float* x = (const float*)d_in[0];
  const float* wgt = (const float*)d_in[1];
  const float* bias = (const float*)d_in[2];
  float* out = (float*)d_out;

  // ws layout: wbg @ 0 (18432 B), bias2w @ 18432 (49152 B)
  uint64_t* wbg = (uint64_t*)d_ws;
  float* bias2w = (float*)((char*)d_ws + 18432);

  cyc_prep<<<IN_CH, 64, 0, stream>>>(wgt, bias, wbg, bias2w);
  cyc_fused<<<BB * 8, 768, 0, stream>>>(x, wbg, bias2w, out);
}

// Round 6
// 197.473 us; speedup vs baseline: 1.3967x; 1.3967x over previous
//
#include <hip/hip_runtime.h>
#include <stdint.h>

// CycleFC 1w1a: out[b,o,h,w] = sum_c sign(x)[b,c,h,w+off(c)] * sign(W)[o,c] + bias[o]
// off(c) = (c+3)%7 - 3, zero-pad OOB. B=64, C=O=384, H=W=32.
//
// Binary-GEMM: pack signs (bit=1 iff <0) into 6 u64 words; out = bias2 - 2*popc(G^WB).
// bias2w[o][w] = bias[o] + Nvalid(w) + 2*popc(WB & ~V(w)) precomputed in prep.
//
// R11: R10 proved the device sustains 3.4 TB/s for this kernel when given
// memory parallelism -> the 70us plateau (2.1 TB/s, VALU 29%) is an access-
// GRANULARITY ceiling: 128B/lane strided reads + 256B scattered stores.
// Split into two homogeneous kernels, no LDS, no barriers:
//  pack: x -> G[b][j][1024] u64 pixel-major planes (3MB, L3-resident).
//        Verified shift+butterfly; 256B-contiguous task stores.
//  gemm: block=(b, 48-o); wave owns 6 o, 36 weight u64 preloaded (uniform ->
//        SGPR, zero in-loop s_load); lane owns 4 consecutive pixels ->
//        float4 stores = 1KB contiguous per wave-instr (4x coarser than R9).
//        G re-read x8 hits L3 (24MB), x itself read exactly once (by pack).

#define IN_CH 384
#define HH 32
#define WW 32
#define BB 64

constexpr uint64_t P7(int t) {
  uint64_t m = 0;
  for (int k = 0; k < 64; ++k)
    if (k % 7 == t) m |= (1ull << k);
  return m;
}
__device__ __constant__ uint64_t Pm[7] = {P7(0), P7(1), P7(2), P7(3), P7(4), P7(5), P7(6)};

// ---------------- prep: one block (1 wave) per output channel o --------------
__global__ __launch_bounds__(64) void cyc_prep(const float* __restrict__ wgt,
                                               const float* __restrict__ bias,
                                               uint64_t* __restrict__ wbg,
                                               float* __restrict__ bias2w) {
  const int o = blockIdx.x;
  const int lane = threadIdx.x;
  __shared__ uint64_t wb_sh[6];
#pragma unroll
  for (int j = 0; j < 6; ++j) {
    uint64_t m = __ballot(wgt[o * IN_CH + j * 64 + lane] < 0.0f);
    if (lane == 0) wb_sh[j] = m;
  }
  __syncthreads();
  if (lane < 6) wbg[o * 6 + lane] = wb_sh[lane];
  if (lane < WW) {
    const int w = lane;
    int nv = 0, corr = 0;
#pragma unroll
    for (int j = 0; j < 6; ++j) {
      uint64_t V = 0;
#pragma unroll
      for (int d = -3; d <= 3; ++d) {
        int wd = w + d;
        if (wd >= 0 && wd < WW) V |= Pm[(d - j + 14) % 7];
      }
      nv += __popcll(V);
      corr += __popcll(wb_sh[j] & ~V);
    }
    // layout [o][w]: gemm bias loads are coalesced float4 per o
    bias2w[o * WW + w] = bias[o] + (float)nv + 2.0f * (float)corr;
  }
}

// ---------------- pack: x -> G, no LDS, no barrier ---------------------------
// block = (b, 4 rows), 768 thr = 12 waves, 2 tasks each. grid = 512.
__global__ __launch_bounds__(768) void cyc_pack(const float* __restrict__ x,
                                                uint32_t* __restrict__ G32) {
  const int t = threadIdx.x;
  const int lane = t & 63, wave = t >> 6;
  const int b = blockIdx.x >> 3;
  const int h0 = (blockIdx.x & 7) * 4;
  const int wcol = lane & 31, hhalf = lane >> 5;
#pragma unroll
  for (int p = 0; p < 2; ++p) {
    const int tau = wave + p * 12;  // 0..23 = (r, j)
    const int r = tau / 6, j = tau % 6;
    const int c = j * 64 + lane;
    const int off = ((c % 7 + 3) % 7) - 3;  // in [-3,3]
    const uint32_t shr = (off > 0) ? (uint32_t)off : 0u;
    const uint32_t shl = (off < 0) ? (uint32_t)(-off) : 0u;
    const float4* xp = reinterpret_cast<const float4*>(
        x + (size_t)((b * IN_CH + c) * HH + h0 + r) * WW);
    uint32_t myw = 0;
#pragma unroll
    for (int i = 0; i < 8; ++i) {
      float4 v = xp[i];
      myw |= (v.x < 0.0f ? 1u : 0u) << (i * 4 + 0);
      myw |= (v.y < 0.0f ? 1u : 0u) << (i * 4 + 1);
      myw |= (v.z < 0.0f ? 1u : 0u) << (i * 4 + 2);
      myw |= (v.w < 0.0f ? 1u : 0u) << (i * 4 + 3);
    }
    // pre-transpose cycle shift: bit w := myw bit (w+off); zero-fill == OOB pad
    uint32_t s = (myw >> shr) << shl;  // one of shr/shl is 0
    // 5-step 32x32 bit transpose across each 32-lane half (verified R7-R10).
    // After: lane (hhalf,wcol) holds bit k = shifted sign of channel
    // j*64 + hhalf*32 + k at pixel column wcol.
    constexpr uint32_t Mt[5] = {0xFFFF0000u, 0xFF00FF00u, 0xF0F0F0F0u,
                                0xCCCCCCCCu, 0xAAAAAAAAu};
#pragma unroll
    for (int stp = 0; stp < 5; ++stp) {
      const int js = 16 >> stp;
      const uint32_t M = Mt[stp];
      uint32_t y = __shfl_xor(s, js);
      s = (lane & js) ? ((s & M) | ((y >> js) & ~M))
                      : ((s & ~M) | ((y << js) & M));
    }
    // u32 half hhalf of u64 G[b][j][pixel], pixel = (h0+r)*32 + wcol.
    // 64 lanes -> 64 consecutive u32 = 256B contiguous store.
    G32[(((size_t)b * 6 + j) * 1024 + (h0 + r) * 32 + wcol) * 2 + hhalf] = s;
  }
}

// ---------------- gemm: G -> out, write-optimal ------------------------------
// block = (b, 48-o chunk), 512 thr = 8 waves, grid = 512. Wave owns 6 o.
// lane owns 4 consecutive pixels -> float4 stores, 1KB contiguous per instr.
__global__ __launch_bounds__(512) void cyc_gemm(const uint64_t* __restrict__ G,
                                                const uint64_t* __restrict__ wbg,
                                                const float* __restrict__ bias2w,
                                                float* __restrict__ out) {
  const int t = threadIdx.x;
  const int lane = t & 63, wave = t >> 6;
  const int b = blockIdx.x >> 3;
  const int oc = blockIdx.x & 7;
  const int o0 = oc * 48 + __builtin_amdgcn_readfirstlane(wave) * 6;

  // 36 weight u64, wave-uniform -> scalar loads, hoisted out of the loop.
  uint64_t Wg[6][6];
  {
    const uint64_t* wp = wbg + (size_t)o0 * 6;
#pragma unroll
    for (int oo = 0; oo < 6; ++oo)
#pragma unroll
      for (int j = 0; j < 6; ++j) Wg[oo][j] = wp[oo * 6 + j];
  }
  // bias: lane's 4 pixels have w = (4*lane)&31 + px (pass-invariant mod 32)
  const int w4 = (4 * lane) & 31;
  float4 bs[6];
#pragma unroll
  for (int oo = 0; oo < 6; ++oo)
    bs[oo] = *reinterpret_cast<const float4*>(bias2w + (o0 + oo) * WW + w4);

  const uint64_t* gb = G + (size_t)b * 6 * 1024;
  float* ob = out + ((size_t)b * IN_CH + o0) * (HH * WW);

#pragma unroll
  for (int pass = 0; pass < 4; ++pass) {
    const int p0 = pass * 256 + 4 * lane;
    // load 4 pixels x 6 planes = 192B/lane; 2x dwordx4 per plane, L3-hit
    uint64_t ga[6], gB[6], gc[6], gd[6];
#pragma unroll
    for (int j = 0; j < 6; ++j) {
      const ulonglong2* gp =
          reinterpret_cast<const ulonglong2*>(gb + (size_t)j * 1024 + p0);
      ulonglong2 u = gp[0], v = gp[1];
      ga[j] = u.x; gB[j] = u.y; gc[j] = v.x; gd[j] = v.y;
    }
#pragma unroll
    for (int oo = 0; oo < 6; ++oo) {
      int m0 = 0, m1 = 0, m2 = 0, m3 = 0;
#pragma unroll
      for (int j = 0; j < 6; ++j) {
        m0 += __popcll(ga[j] ^ Wg[oo][j]);
        m1 += __popcll(gB[j] ^ Wg[oo][j]);
        m2 += __popcll(gc[j] ^ Wg[oo][j]);
        m3 += __popcll(gd[j] ^ Wg[oo][j]);
      }
      float4 r;
      r.x = bs[oo].x - 2.0f * (float)m0;
      r.y = bs[oo].y - 2.0f * (float)m1;
      r.z = bs[oo].z - 2.0f * (float)m2;
      r.w = bs[oo].w - 2.0f * (float)m3;
      // 64 lanes x 16B consecutive -> 1KB contiguous store
      *reinterpret_cast<float4*>(ob + (size_t)oo * (HH * WW) + p0) = r;
    }
  }
}

extern "C" void kernel_launch(void* const* d_in, const int* in_sizes, int n_in,
                              void* d_out, int out_size, void* d_ws, size_t ws_size,
                              hipStream_t stream) {
  const float* x = (const float*)d_in[0];
  const float* wgt = (const float*)d_in[1];
  const float* bias = (const float*)d_in[2];
  float* out = (float*)d_out;

  // ws layout: wbg @ 0 (18432 B), bias2w @ 18432 (49152 B), G @ 67584 (3 MB)
  uint64_t* wbg = (uint64_t*)d_ws;
  float* bias2w = (float*)((char*)d_ws + 18432);
  uint64_t* G = (uint64_t*)((char*)d_ws + 67584);

  cyc_prep<<<IN_CH, 64, 0, stream>>>(wgt, bias, wbg, bias2w);
  cyc_pack<<<BB * 8, 768, 0, stream>>>(x, (uint32_t*)G);
  cyc_gemm<<<BB * 8, 512, 0, stream>>>(G, wbg, bias2w, out);
}